// Round 9
// baseline (295.320 us; speedup 1.0000x reference)
//
#include <hip/hip_runtime.h>
#include <hip/hip_bf16.h>
#include <cstdint>
#include <cstddef>

#define N_TOK 8192
#define D_IN  1024
#define D_OUT 1024
#define N_EXP 8
#define KTOT  (N_EXP * D_IN)

#define BM    256
#define BN    128
#define BKH   32          // half-K step
#define NSTEP 256         // KTOT / BKH

typedef __attribute__((ext_vector_type(8))) short short8;
typedef __attribute__((ext_vector_type(8))) unsigned short ushort8;
typedef __attribute__((ext_vector_type(4))) float f32x4;

__device__ __forceinline__ unsigned short f2bf(float f) {
    union { float f; unsigned int u; } v; v.f = f;
    return (unsigned short)((v.u + 0x7FFFu + ((v.u >> 16) & 1u)) >> 16);
}

__device__ __forceinline__ void load_lds16(const void* g, void* l) {
    __builtin_amdgcn_global_load_lds(
        (const __attribute__((address_space(1))) void*)g,
        (__attribute__((address_space(3))) void*)l,
        16, 0, 0);
}

// ---------------------------------------------------------------------------
// Fused prep, 4096 blocks (R8 version, UNCHANGED):
//   [0,2048)    : W transpose -> Wt[o][e*1024+i] bf16
//   [2048,4096) : gate softmax (gW staged in LDS) + x->bf16
// ---------------------------------------------------------------------------
__global__ __launch_bounds__(256) void prep_kernel(
    const float* __restrict__ x, const float* __restrict__ gW,
    const float* __restrict__ gbias, const float* __restrict__ W,
    unsigned short* __restrict__ xb, unsigned short* __restrict__ Wt,
    float* __restrict__ g_t) {
    const int b = blockIdx.x;
    const int t = threadIdx.x;

    __shared__ __align__(16) float smem[8 * 1028];   // 32.9 KB (union)

    if (b < 2048) {
        float (*tile)[65] = (float(*)[65])smem;
        const int e  = b >> 8;
        const int i0 = ((b >> 4) & 15) * 64;
        const int o0 = (b & 15) * 64;

        const int rr = t >> 4;
        const int rc = (t & 15) * 4;
#pragma unroll
        for (int j = 0; j < 4; ++j) {
            const float4 v = *(const float4*)(
                W + ((size_t)e * D_IN + (i0 + rr + 16 * j)) * D_OUT + o0 + rc);
            tile[rr + 16 * j][rc + 0] = v.x;
            tile[rr + 16 * j][rc + 1] = v.y;
            tile[rr + 16 * j][rc + 2] = v.z;
            tile[rr + 16 * j][rc + 3] = v.w;
        }
        __syncthreads();
        const int ow = t >> 2;
        const int c  = (t & 3) * 16;
        ushort8 v0, v1;
#pragma unroll
        for (int j = 0; j < 8; ++j) v0[j] = f2bf(tile[c + j][ow]);
#pragma unroll
        for (int j = 0; j < 8; ++j) v1[j] = f2bf(tile[c + 8 + j][ow]);
        unsigned short* dst = Wt + (size_t)(o0 + ow) * KTOT + e * D_IN + i0 + c;
        *(ushort8*)dst = v0;
        *(ushort8*)(dst + 8) = v1;
    } else {
        float (*gwT)[1028] = (float(*)[1028])smem;
#pragma unroll
        for (int r = 0; r < 32; ++r) {
            const int flat = t + 256 * r;          // = i*8 + e
            gwT[flat & 7][flat >> 3] = gW[flat];
        }
        __syncthreads();

        const int lane = t & 63;
        const int n    = (b - 2048) * 4 + (t >> 6);

        float acc[8];
#pragma unroll
        for (int e = 0; e < 8; ++e) acc[e] = 0.f;
#pragma unroll
        for (int jj = 0; jj < 4; ++jj) {
            const int i = 256 * jj + 4 * lane;
            const float4 xv = *(const float4*)(x + (size_t)n * D_IN + i);
            ushort4 u;
            u.x = f2bf(xv.x); u.y = f2bf(xv.y);
            u.z = f2bf(xv.z); u.w = f2bf(xv.w);
            *(ushort4*)(xb + (size_t)n * D_IN + i) = u;
#pragma unroll
            for (int e = 0; e < 8; ++e) {
                const float4 wv = *(const float4*)&gwT[e][i];
                acc[e] += xv.x * wv.x + xv.y * wv.y
                        + xv.z * wv.z + xv.w * wv.w;
            }
        }
#pragma unroll
        for (int off = 32; off > 0; off >>= 1) {
#pragma unroll
            for (int e = 0; e < 8; ++e) acc[e] += __shfl_down(acc[e], off);
        }
        if (lane == 0) {
            float lg[8], mx = -1e30f;
#pragma unroll
            for (int e = 0; e < 8; ++e) {
                lg[e] = acc[e] + gbias[e];
                mx = fmaxf(mx, lg[e]);
            }
            float s = 0.f;
#pragma unroll
            for (int e = 0; e < 8; ++e) { lg[e] = expf(lg[e] - mx); s += lg[e]; }
            const float inv = 1.f / s;
#pragma unroll
            for (int e = 0; e < 8; ++e)
                g_t[(size_t)e * N_TOK + n] = lg[e] * inv;
        }
    }
}

// ---------------------------------------------------------------------------
// GEMM v17: same BM256xBN128 block tile / supertile / swizzles / rescale as
// v13, but 256 threads = 4 waves with WAVE TILE 128x64 (2Mx2N):
//   - frag-read bytes drop 2.0 -> 1.5 B per output per K-step
//     (port 88KB -> 72KB per CU-step; pipe 621 cyc; floor ~850-900 cyc
//     vs v13's measured 1372).
//   - acc 8x4 f32x4 (128 VGPR); 1 wave/SIMD -> ~240 VGPR budget fine.
//   - reads for step h+1 interleaved per ni-group (bv[ni] dead after its
//     group); stage(h+3) issued at step TOP (max latency budget);
//     ENDW vmcnt(6) keeps one full stage (6 loads) in flight across every
//     barrier. 4 LDS slots, depth-3. One barrier per step.
// FIFO proof: ENDW(h) queue = stage(h+2)[6] + stage(h+3)[6]; vmcnt(6)
// drains stage(h+2), which step h+1's interleaved reads need. Prologue
// stages 0,1,2 and drains 0,1 (vmcnt(6)). Tail: ENDW(252)=vmcnt(6) drains
// 254; ENDW(253)=vmcnt(0) drains 255; steps 254/255 need no barrier.
// ---------------------------------------------------------------------------
__global__ __launch_bounds__(256, 1) void moe_gemm17_kernel(
    const unsigned short* __restrict__ xb,   // [N_TOK][D_IN] bf16
    const unsigned short* __restrict__ Wt,   // [D_OUT][KTOT] bf16
    const float* __restrict__ bias,          // [N_EXP][D_OUT]
    const float* __restrict__ g_t,           // [N_EXP][N_TOK]
    float* __restrict__ out) {               // [N_TOK][D_OUT]
    __shared__ __align__(16) unsigned short A4[4][BM * BKH];  // 64 KB
    __shared__ __align__(16) unsigned short B4[4][BN * BKH];  // 32 KB
    __shared__ __align__(16) float g_s[N_EXP][BM];            // 8 KB
    __shared__ __align__(16) float r_s[N_EXP][BM];            // 8 KB
    __shared__ __align__(16) float b_s[N_EXP][BN];            // 4 KB

    const int t    = threadIdx.x;
    const int lane = t & 63;
    const int ln15 = lane & 15;
    const int quad = lane >> 4;
    const int wave = t >> 6;             // 0..3
    const int wm0  = (wave >> 1) * 128;  // 0,128
    const int wn0  = (wave & 1) * 64;    // 0,64

    // XCD super-tile (R2-verified): flat%8 = XCD owns 4M x 8N rectangle.
    const int flat = blockIdx.x + 8 * blockIdx.y;   // grid (8, 32)
    const int bn0  = ((flat >> 3) & 7) * BN;
    const int bm0  = ((flat & 7) * 4 + (flat >> 6)) * BM;

    for (int j = t; j < N_EXP * BM; j += 256)
        g_s[j >> 8][j & 255] = g_t[(size_t)(j >> 8) * N_TOK + bm0 + (j & 255)];
    for (int j = t; j < N_EXP * BN; j += 256)
        b_s[j >> 7][j & 127] = bias[(size_t)(j >> 7) * D_OUT + bn0 + (j & 127)];
    __syncthreads();
    {
        float d[N_EXP];
#pragma unroll
        for (int e = 0; e < N_EXP; ++e) d[e] = fmaxf(g_s[e][t], 1e-30f);
#pragma unroll
        for (int e = 1; e < N_EXP; ++e) r_s[e][t] = d[e - 1] / d[e];
        r_s[0][t] = d[N_EXP - 1];
    }
    __syncthreads();   // r_s ready

    f32x4 acc[8][4];
#pragma unroll
    for (int mi = 0; mi < 8; ++mi)
#pragma unroll
        for (int ni = 0; ni < 4; ++ni)
            acc[mi][ni] = (f32x4){0.f, 0.f, 0.f, 0.f};

    // Staging: thread t fills rows (t>>2)+64j, chunk t&3; swizzled global
    // source so slot chunk c' holds global chunk c'^((row>>1)&3).
    // (row>>1)&3 = (t>>3)&3 independent of j (64j contributes 0 mod 4).
    const int csw  = ((t & 3) ^ ((t >> 3) & 3)) * 8;
    const unsigned short* gA = xb + (size_t)(bm0 + (t >> 2)) * D_IN + csw;
    const unsigned short* gB = Wt + (size_t)(bn0 + (t >> 2)) * (size_t)KTOT + csw;
    const int wb = wave * 16 * BKH;     // wave-uniform LDS base step

    // Fragment reads: chunk slot = quad ^ ((ln15>>1)&3)  (0-conflict, v13)
    const int ksw  = (quad ^ ((ln15 >> 1) & 3)) * 8;
    const int aoff = (wm0 + ln15) * BKH + ksw;
    const int boff = (wn0 + ln15) * BKH + ksw;

    // Named register buffers (static indexing — rule #20).
    short8 afA[8], afB[8], bvA[4], bvB[4];

#define STAGE(h_, slot_)                                                      \
  {                                                                           \
    load_lds16(gA + ((h_) & 31) * BKH,               &A4[slot_][wb]);         \
    load_lds16(gA + 64 * D_IN + ((h_) & 31) * BKH,   &A4[slot_][2048 + wb]);  \
    load_lds16(gA + 128 * D_IN + ((h_) & 31) * BKH,  &A4[slot_][4096 + wb]);  \
    load_lds16(gA + 192 * D_IN + ((h_) & 31) * BKH,  &A4[slot_][6144 + wb]);  \
    load_lds16(gB + (size_t)(h_) * BKH,              &B4[slot_][wb]);         \
    load_lds16(gB + 64 * (size_t)KTOT + (size_t)(h_) * BKH,                   \
               &B4[slot_][2048 + wb]);                                        \
  }

    // prologue: stage slots 0,1,2 (18 loads); vmcnt(6) drains 0,1; barrier;
    // read slot-0 fragments.
    STAGE(0, 0) STAGE(1, 1) STAGE(2, 2)
    asm volatile("s_waitcnt vmcnt(6)" ::: "memory");
    __builtin_amdgcn_s_barrier();
    __builtin_amdgcn_sched_barrier(0);
#pragma unroll
    for (int mi = 0; mi < 8; ++mi)
        afA[mi] = *(const short8*)(&A4[0][0] + aoff + mi * 16 * BKH);
#pragma unroll
    for (int ni = 0; ni < 4; ++ni)
        bvA[ni] = *(const short8*)(&B4[0][0] + boff + ni * 16 * BKH);

#define MFMA8(CUR, ni_)                                                       \
    _Pragma("unroll") for (int mi = 0; mi < 8; ++mi)                          \
        acc[mi][ni_] = __builtin_amdgcn_mfma_f32_16x16x32_bf16(               \
            af##CUR[mi], bv##CUR[ni_], acc[mi][ni_], 0, 0, 0);

// Step h: lgkm0 | rescale? | stage(h+3) | 4 ni-groups of 8 MFMA, each
// followed by reads of next-step frags (bv[ni] dead after group ni).
#define STEP(h_, CUR, NXT, DO_STAGE, DO_READ)                                 \
  {                                                                           \
    const unsigned short* An_ = &A4[((h_) + 1) & 3][0];                       \
    const unsigned short* Bn_ = &B4[((h_) + 1) & 3][0];                       \
    asm volatile("s_waitcnt lgkmcnt(0)" ::: "memory");                        \
    __builtin_amdgcn_sched_barrier(0);                                        \
    if ((h_) && !((h_) & 31)) {  /* telescoping rescale at expert entry */    \
      const int e_ = (h_) >> 5;                                               \
      _Pragma("unroll") for (int mi = 0; mi < 8; ++mi) {                      \
        const f32x4 rv = *(const f32x4*)&r_s[e_][wm0 + mi * 16 + quad * 4];   \
        _Pragma("unroll") for (int ni = 0; ni < 4; ++ni)                      \
          _Pragma("unroll") for (int r = 0; r < 4; ++r)                       \
            acc[mi][ni][r] *= rv[r];                                          \
      }                                                                       \
    }                                                                         \
    if (DO_STAGE) STAGE((h_) + 3, ((h_) + 3) & 3)                             \
    __builtin_amdgcn_sched_barrier(0);                                        \
    __builtin_amdgcn_s_setprio(1);                                            \
    MFMA8(CUR, 0)                                                             \
    __builtin_amdgcn_sched_barrier(0);                                        \
    if (DO_READ) {                                                            \
      bv##NXT[0] = *(const short8*)(Bn_ + boff + 0 * 16 * BKH);               \
      af##NXT[0] = *(const short8*)(An_ + aoff + 0 * 16 * BKH);               \
      af##NXT[1] = *(const short8*)(An_ + aoff + 1 * 16 * BKH);               \
    }                                                                         \
    __builtin_amdgcn_sched_barrier(0);                                        \
    MFMA8(CUR, 1)                                                             \
    __builtin_amdgcn_sched_barrier(0);                                        \
    if (DO_READ) {                                                            \
      bv##NXT[1] = *(const short8*)(Bn_ + boff + 1 * 16 * BKH);               \
      af##NXT[2] = *(const short8*)(An_ + aoff + 2 * 16 * BKH);               \
      af##NXT[3] = *(const short8*)(An_ + aoff + 3 * 16 * BKH);               \
    }                                                                         \
    __builtin_amdgcn_sched_barrier(0);                                        \
    MFMA8(CUR, 2)                                                             \
    __builtin_amdgcn_sched_barrier(0);                                        \
    if (DO_READ) {                                                            \
      bv##NXT[2] = *(const short8*)(Bn_ + boff + 2 * 16 * BKH);               \
      af##NXT[4] = *(const short8*)(An_ + aoff + 4 * 16 * BKH);               \
      af##NXT[5] = *(const short8*)(An_ + aoff + 5 * 16 * BKH);               \
    }                                                                         \
    __builtin_amdgcn_sched_barrier(0);                                        \
    MFMA8(CUR, 3)                                                             \
    __builtin_amdgcn_sched_barrier(0);                                        \
    if (DO_READ) {                                                            \
      bv##NXT[3] = *(const short8*)(Bn_ + boff + 3 * 16 * BKH);               \
      af##NXT[6] = *(const short8*)(An_ + aoff + 6 * 16 * BKH);               \
      af##NXT[7] = *(const short8*)(An_ + aoff + 7 * 16 * BKH);               \
    }                                                                         \
    __builtin_amdgcn_s_setprio(0);                                            \
    __builtin_amdgcn_sched_barrier(0);                                        \
  }

#define ENDW(N_)                                                              \
  asm volatile("s_waitcnt vmcnt(" #N_ ")" ::: "memory");                      \
  __builtin_amdgcn_s_barrier();                                               \
  __builtin_amdgcn_sched_barrier(0);

    for (int h = 0; h < NSTEP - 4; h += 2) {   // pairs (0,1)..(250,251)
        STEP(h, A, B, 1, 1);
        ENDW(6);
        STEP(h + 1, B, A, 1, 1);
        ENDW(6);
    }
    STEP(252, A, B, 1, 1);   // stages slot 255 (last)
    ENDW(6);                 // drains stage(254) — read during step 253
    STEP(253, B, A, 0, 1);
    ENDW(0);                 // drains stage(255) — read during step 254
    STEP(254, A, B, 0, 1);   // reads frags 255; nothing outstanding
    STEP(255, B, A, 0, 0);

#undef STEP
#undef MFMA8
#undef ENDW
#undef STAGE

    // final telescope scale by d[7], then add sum_e g_e * b[e][col]
#pragma unroll
    for (int mi = 0; mi < 8; ++mi) {
        const f32x4 fin = *(const f32x4*)&r_s[0][wm0 + mi * 16 + quad * 4];
#pragma unroll
        for (int ni = 0; ni < 4; ++ni)
#pragma unroll
            for (int r = 0; r < 4; ++r) acc[mi][ni][r] *= fin[r];
    }
#pragma unroll
    for (int e = 0; e < N_EXP; ++e) {
        f32x4 gv[8];
        float bb[4];
#pragma unroll
        for (int mi = 0; mi < 8; ++mi)
            gv[mi] = *(const f32x4*)&g_s[e][wm0 + mi * 16 + quad * 4];
#pragma unroll
        for (int ni = 0; ni < 4; ++ni) bb[ni] = b_s[e][wn0 + ni * 16 + ln15];
#pragma unroll
        for (int mi = 0; mi < 8; ++mi)
#pragma unroll
            for (int ni = 0; ni < 4; ++ni)
#pragma unroll
                for (int r = 0; r < 4; ++r)
                    acc[mi][ni][r] += gv[mi][r] * bb[ni];
    }

#pragma unroll
    for (int mi = 0; mi < 8; ++mi) {
#pragma unroll
        for (int ni = 0; ni < 4; ++ni) {
            const int col  = bn0 + wn0 + ni * 16 + ln15;
            const int row0 = bm0 + wm0 + mi * 16 + quad * 4;
#pragma unroll
            for (int r = 0; r < 4; ++r)
                out[(size_t)(row0 + r) * D_OUT + col] = acc[mi][ni][r];
        }
    }
}

// ---------------------------------------------------------------------------
extern "C" void kernel_launch(void* const* d_in, const int* in_sizes, int n_in,
                              void* d_out, int out_size, void* d_ws, size_t ws_size,
                              hipStream_t stream) {
    const float* x  = (const float*)d_in[0];
    const float* W  = (const float*)d_in[1];
    const float* b  = (const float*)d_in[2];
    const float* gW = (const float*)d_in[3];
    const float* gb = (const float*)d_in[4];
    float* out = (float*)d_out;

    unsigned short* xb  = (unsigned short*)d_ws;                 // 16 MB
    unsigned short* Wt  = xb + (size_t)N_TOK * D_IN;             // 16 MB
    float*          g_t = (float*)(Wt + (size_t)D_OUT * KTOT);   // 256 KB

    prep_kernel<<<4096, 256, 0, stream>>>(x, gW, gb, W, xb, Wt, g_t);
    moe_gemm17_kernel<<<dim3(D_OUT / BN, N_TOK / BM), 256, 0, stream>>>(
        xb, Wt, b, g_t, out);
}

// Round 10
// 249.889 us; speedup vs baseline: 1.1818x; 1.1818x over previous
//
#include <hip/hip_runtime.h>
#include <hip/hip_bf16.h>
#include <cstdint>
#include <cstddef>

#define N_TOK 8192
#define D_IN  1024
#define D_OUT 1024
#define N_EXP 8
#define KTOT  (N_EXP * D_IN)

#define BM    256
#define BN    128
#define BKH   32          // half-K step
#define NSTEP 256         // KTOT / BKH

typedef __attribute__((ext_vector_type(8))) short short8;
typedef __attribute__((ext_vector_type(8))) unsigned short ushort8;
typedef __attribute__((ext_vector_type(4))) float f32x4;

__device__ __forceinline__ unsigned short f2bf(float f) {
    union { float f; unsigned int u; } v; v.f = f;
    return (unsigned short)((v.u + 0x7FFFu + ((v.u >> 16) & 1u)) >> 16);
}

__device__ __forceinline__ void load_lds16(const void* g, void* l) {
    __builtin_amdgcn_global_load_lds(
        (const __attribute__((address_space(1))) void*)g,
        (__attribute__((address_space(3))) void*)l,
        16, 0, 0);
}

// ---------------------------------------------------------------------------
// Fused prep, 4096 blocks (R8 version — best measured):
//   [0,2048)    : W transpose -> Wt[o][e*1024+i] bf16
//   [2048,4096) : gate softmax (gW staged in LDS, R8 fix: -13us) + x->bf16
// ---------------------------------------------------------------------------
__global__ __launch_bounds__(256) void prep_kernel(
    const float* __restrict__ x, const float* __restrict__ gW,
    const float* __restrict__ gbias, const float* __restrict__ W,
    unsigned short* __restrict__ xb, unsigned short* __restrict__ Wt,
    float* __restrict__ g_t) {
    const int b = blockIdx.x;
    const int t = threadIdx.x;

    __shared__ __align__(16) float smem[8 * 1028];   // 32.9 KB (union)

    if (b < 2048) {
        float (*tile)[65] = (float(*)[65])smem;
        const int e  = b >> 8;
        const int i0 = ((b >> 4) & 15) * 64;
        const int o0 = (b & 15) * 64;

        const int rr = t >> 4;
        const int rc = (t & 15) * 4;
#pragma unroll
        for (int j = 0; j < 4; ++j) {
            const float4 v = *(const float4*)(
                W + ((size_t)e * D_IN + (i0 + rr + 16 * j)) * D_OUT + o0 + rc);
            tile[rr + 16 * j][rc + 0] = v.x;
            tile[rr + 16 * j][rc + 1] = v.y;
            tile[rr + 16 * j][rc + 2] = v.z;
            tile[rr + 16 * j][rc + 3] = v.w;
        }
        __syncthreads();
        const int ow = t >> 2;
        const int c  = (t & 3) * 16;
        ushort8 v0, v1;
#pragma unroll
        for (int j = 0; j < 8; ++j) v0[j] = f2bf(tile[c + j][ow]);
#pragma unroll
        for (int j = 0; j < 8; ++j) v1[j] = f2bf(tile[c + 8 + j][ow]);
        unsigned short* dst = Wt + (size_t)(o0 + ow) * KTOT + e * D_IN + i0 + c;
        *(ushort8*)dst = v0;
        *(ushort8*)(dst + 8) = v1;
    } else {
        float (*gwT)[1028] = (float(*)[1028])smem;
#pragma unroll
        for (int r = 0; r < 32; ++r) {
            const int flat = t + 256 * r;          // = i*8 + e
            gwT[flat & 7][flat >> 3] = gW[flat];
        }
        __syncthreads();

        const int lane = t & 63;
        const int n    = (b - 2048) * 4 + (t >> 6);

        float acc[8];
#pragma unroll
        for (int e = 0; e < 8; ++e) acc[e] = 0.f;
#pragma unroll
        for (int jj = 0; jj < 4; ++jj) {
            const int i = 256 * jj + 4 * lane;
            const float4 xv = *(const float4*)(x + (size_t)n * D_IN + i);
            ushort4 u;
            u.x = f2bf(xv.x); u.y = f2bf(xv.y);
            u.z = f2bf(xv.z); u.w = f2bf(xv.w);
            *(ushort4*)(xb + (size_t)n * D_IN + i) = u;
#pragma unroll
            for (int e = 0; e < 8; ++e) {
                const float4 wv = *(const float4*)&gwT[e][i];
                acc[e] += xv.x * wv.x + xv.y * wv.y
                        + xv.z * wv.z + xv.w * wv.w;
            }
        }
#pragma unroll
        for (int off = 32; off > 0; off >>= 1) {
#pragma unroll
            for (int e = 0; e < 8; ++e) acc[e] += __shfl_down(acc[e], off);
        }
        if (lane == 0) {
            float lg[8], mx = -1e30f;
#pragma unroll
            for (int e = 0; e < 8; ++e) {
                lg[e] = acc[e] + gbias[e];
                mx = fmaxf(mx, lg[e]);
            }
            float s = 0.f;
#pragma unroll
            for (int e = 0; e < 8; ++e) { lg[e] = expf(lg[e] - mx); s += lg[e]; }
            const float inv = 1.f / s;
#pragma unroll
            for (int e = 0; e < 8; ++e)
                g_t[(size_t)e * N_TOK + n] = lg[e] * inv;
        }
    }
}

// ---------------------------------------------------------------------------
// GEMM v13 — best measured (145.7us, MfmaUtil 42.4, 0 conflicts, 941 TF).
// BM256xBN128, 8 waves 64x64, 4 LDS slots depth-3, counted vmcnt(3), XCD
// 4Mx8N super-tile, XOR swizzle, interleaved MFMA/ds_read reg-dbuf,
// telescoping gate rescale. Structural ceiling of this design space:
// wave 64x64 is optimal frag-bytes/output at 2 waves/SIMD (128x64 -> 1
// wave/SIMD refuted R9; B-bypass refuted R6/R7; barrier-free refuted R3).
// ---------------------------------------------------------------------------
__global__ __launch_bounds__(512, 1) void moe_gemm13_kernel(
    const unsigned short* __restrict__ xb,   // [N_TOK][D_IN] bf16
    const unsigned short* __restrict__ Wt,   // [D_OUT][KTOT] bf16
    const float* __restrict__ bias,          // [N_EXP][D_OUT]
    const float* __restrict__ g_t,           // [N_EXP][N_TOK]
    float* __restrict__ out) {               // [N_TOK][D_OUT]
    __shared__ __align__(16) unsigned short A4[4][BM * BKH];  // 64 KB
    __shared__ __align__(16) unsigned short B4[4][BN * BKH];  // 32 KB
    __shared__ __align__(16) float g_s[N_EXP][BM];            // 8 KB
    __shared__ __align__(16) float r_s[N_EXP][BM];            // 8 KB
    __shared__ __align__(16) float b_s[N_EXP][BN];            // 4 KB

    const int t    = threadIdx.x;
    const int lane = t & 63;
    const int ln15 = lane & 15;
    const int quad = lane >> 4;
    const int wave = t >> 6;             // 0..7
    const int wm0  = (wave >> 1) * 64;   // 0,64,128,192
    const int wn0  = (wave & 1) * 64;    // 0,64

    // XCD super-tile: flat%8 = XCD; XCD owns M-rows [4*xcd,4*xcd+4) x 8 N-cols
    // -> per-XCD per-expert working set 4MB = L2 (R2: FETCH 533->79MB).
    const int flat = blockIdx.x + 8 * blockIdx.y;   // grid (8, 32)
    const int bn0  = ((flat >> 3) & 7) * BN;
    const int bm0  = ((flat & 7) * 4 + (flat >> 6)) * BM;

    for (int j = t; j < N_EXP * BM; j += 512)
        g_s[j >> 8][j & 255] = g_t[(size_t)(j >> 8) * N_TOK + bm0 + (j & 255)];
    for (int j = t; j < N_EXP * BN; j += 512)
        b_s[j >> 7][j & 127] = bias[(size_t)(j >> 7) * D_OUT + bn0 + (j & 127)];
    __syncthreads();
    if (t < BM) {
        float d[N_EXP];
#pragma unroll
        for (int e = 0; e < N_EXP; ++e) d[e] = fmaxf(g_s[e][t], 1e-30f);
#pragma unroll
        for (int e = 1; e < N_EXP; ++e) r_s[e][t] = d[e - 1] / d[e];
        r_s[0][t] = d[N_EXP - 1];
    }
    __syncthreads();   // r_s ready

    f32x4 acc[4][4];
#pragma unroll
    for (int mi = 0; mi < 4; ++mi)
#pragma unroll
        for (int ni = 0; ni < 4; ++ni)
            acc[mi][ni] = (f32x4){0.f, 0.f, 0.f, 0.f};

    // Staging: thread t fills slot (row t>>2, chunk t&3); swizzled global
    // source so slot chunk c' holds global chunk c'^((row>>1)&3).
    const int srow = t >> 2;
    const int csw  = ((t & 3) ^ ((t >> 3) & 3)) * 8;
    const unsigned short* gA = xb + (size_t)(bm0 + srow) * D_IN + csw;
    const unsigned short* gB = Wt + (size_t)(bn0 + srow) * (size_t)KTOT + csw;
    const int wrow = wave * 16 * BKH;   // wave-uniform LDS base

    // Fragment reads: chunk slot = quad ^ ((ln15>>1)&3)  (verified 0-conflict)
    const int ksw  = (quad ^ ((ln15 >> 1) & 3)) * 8;
    const int aoff = (wm0 + ln15) * BKH + ksw;
    const int boff = (wn0 + ln15) * BKH + ksw;

    // Two named fragment register buffers (static indexing — rule #20).
    short8 afA[4], bvA[4], afB[4], bvB[4];

    // prologue: stage slots 0,1,2; vmcnt(3) -> slots 0,1 landed; barrier;
    // read slot-0 fragments into buffer A.
#pragma unroll
    for (int s = 0; s < 3; ++s) {
        load_lds16(gA + s * BKH,              &A4[s][wrow]);
        load_lds16(gA + 128 * D_IN + s * BKH, &A4[s][128 * BKH + wrow]);
        load_lds16(gB + (size_t)s * BKH,      &B4[s][wrow]);
    }
    asm volatile("s_waitcnt vmcnt(3)" ::: "memory");
    __builtin_amdgcn_s_barrier();
    __builtin_amdgcn_sched_barrier(0);
#pragma unroll
    for (int mi = 0; mi < 4; ++mi)
        afA[mi] = *(const short8*)(&A4[0][0] + aoff + mi * 16 * BKH);
#pragma unroll
    for (int ni = 0; ni < 4; ++ni)
        bvA[ni] = *(const short8*)(&B4[0][0] + boff + ni * 16 * BKH);

#define MFMA4(CUR, mi_)                                                       \
    _Pragma("unroll") for (int ni = 0; ni < 4; ++ni)                          \
        acc[mi_][ni] = __builtin_amdgcn_mfma_f32_16x16x32_bf16(               \
            af##CUR[mi_], bv##CUR[ni], acc[mi_][ni], 0, 0, 0);

#define STEP(h_, CUR, NXT, DO_STAGE, DO_READ)                                 \
  {                                                                           \
    const int hs_ = (h_) + 3;                                                 \
    const unsigned short* An_ = &A4[((h_) + 1) & 3][0];                       \
    const unsigned short* Bn_ = &B4[((h_) + 1) & 3][0];                       \
    asm volatile("s_waitcnt lgkmcnt(0)" ::: "memory");                        \
    __builtin_amdgcn_sched_barrier(0);                                        \
    if ((h_) && !((h_) & 31)) {  /* telescoping rescale at expert entry */    \
      const int e_ = (h_) >> 5;                                               \
      _Pragma("unroll") for (int mi = 0; mi < 4; ++mi) {                      \
        const f32x4 rv = *(const f32x4*)&r_s[e_][wm0 + mi * 16 + quad * 4];   \
        _Pragma("unroll") for (int ni = 0; ni < 4; ++ni)                      \
          _Pragma("unroll") for (int r = 0; r < 4; ++r)                       \
            acc[mi][ni][r] *= rv[r];                                          \
      }                                                                       \
    }                                                                         \
    __builtin_amdgcn_s_setprio(1);                                            \
    MFMA4(CUR, 0)                                                             \
    __builtin_amdgcn_sched_barrier(0);                                        \
    if (DO_READ) {                                                            \
      af##NXT[0] = *(const short8*)(An_ + aoff + 0 * 16 * BKH);               \
      af##NXT[1] = *(const short8*)(An_ + aoff + 1 * 16 * BKH);               \
    }                                                                         \
    __builtin_amdgcn_sched_barrier(0);                                        \
    MFMA4(CUR, 1)                                                             \
    __builtin_amdgcn_sched_barrier(0);                                        \
    if (DO_READ) {                                                            \
      af##NXT[2] = *(const short8*)(An_ + aoff + 2 * 16 * BKH);               \
      af##NXT[3] = *(const short8*)(An_ + aoff + 3 * 16 * BKH);               \
    }                                                                         \
    __builtin_amdgcn_sched_barrier(0);                                        \
    MFMA4(CUR, 2)                                                             \
    __builtin_amdgcn_sched_barrier(0);                                        \
    if (DO_READ) {                                                            \
      _Pragma("unroll") for (int ni = 0; ni < 4; ++ni)                        \
        bv##NXT[ni] = *(const short8*)(Bn_ + boff + ni * 16 * BKH);           \
    }                                                                         \
    __builtin_amdgcn_sched_barrier(0);                                        \
    MFMA4(CUR, 3)                                                             \
    __builtin_amdgcn_s_setprio(0);                                            \
    __builtin_amdgcn_sched_barrier(0);                                        \
    if (DO_STAGE) {                                                           \
      load_lds16(gA + ((hs_) & 31) * BKH,              &A4[(hs_) & 3][wrow]); \
      load_lds16(gA + 128 * D_IN + ((hs_) & 31) * BKH,                        \
                 &A4[(hs_) & 3][128 * BKH + wrow]);                           \
      load_lds16(gB + (size_t)(hs_) * BKH,             &B4[(hs_) & 3][wrow]); \
    }                                                                         \
  }

#define ENDW(N_)                                                              \
  asm volatile("s_waitcnt vmcnt(" #N_ ")" ::: "memory");                      \
  __builtin_amdgcn_s_barrier();                                               \
  __builtin_amdgcn_sched_barrier(0);

    for (int h = 0; h < NSTEP - 4; h += 2) {   // pairs (0,1)..(250,251)
        STEP(h, A, B, 1, 1);
        ENDW(3);
        STEP(h + 1, B, A, 1, 1);
        ENDW(3);
    }
    STEP(252, A, B, 1, 1);   // stages slot 255 (last)
    ENDW(3);                 // stage(254) landed (read next step)
    STEP(253, B, A, 0, 1);
    ENDW(0);                 // stage(255) landed (read next step)
    STEP(254, A, B, 0, 1);   // reads slot 255; nothing outstanding -> no bar
    STEP(255, B, A, 0, 0);

#undef STEP
#undef MFMA4
#undef ENDW

    // final telescope scale by d[7], then add sum_e g_e * b[e][col]
#pragma unroll
    for (int mi = 0; mi < 4; ++mi) {
        const f32x4 fin = *(const f32x4*)&r_s[0][wm0 + mi * 16 + quad * 4];
#pragma unroll
        for (int ni = 0; ni < 4; ++ni)
#pragma unroll
            for (int r = 0; r < 4; ++r) acc[mi][ni][r] *= fin[r];
    }
#pragma unroll
    for (int e = 0; e < N_EXP; ++e) {
        f32x4 gv[4];
        float bb[4];
#pragma unroll
        for (int mi = 0; mi < 4; ++mi)
            gv[mi] = *(const f32x4*)&g_s[e][wm0 + mi * 16 + quad * 4];
#pragma unroll
        for (int ni = 0; ni < 4; ++ni) bb[ni] = b_s[e][wn0 + ni * 16 + ln15];
#pragma unroll
        for (int mi = 0; mi < 4; ++mi)
#pragma unroll
            for (int ni = 0; ni < 4; ++ni)
#pragma unroll
                for (int r = 0; r < 4; ++r)
                    acc[mi][ni][r] += gv[mi][r] * bb[ni];
    }

#pragma unroll
    for (int mi = 0; mi < 4; ++mi) {
#pragma unroll
        for (int ni = 0; ni < 4; ++ni) {
            const int col  = bn0 + wn0 + ni * 16 + ln15;
            const int row0 = bm0 + wm0 + mi * 16 + quad * 4;
#pragma unroll
            for (int r = 0; r < 4; ++r)
                out[(size_t)(row0 + r) * D_OUT + col] = acc[mi][ni][r];
        }
    }
}

// ---------------------------------------------------------------------------
extern "C" void kernel_launch(void* const* d_in, const int* in_sizes, int n_in,
                              void* d_out, int out_size, void* d_ws, size_t ws_size,
                              hipStream_t stream) {
    const float* x  = (const float*)d_in[0];
    const float* W  = (const float*)d_in[1];
    const float* b  = (const float*)d_in[2];
    const float* gW = (const float*)d_in[3];
    const float* gb = (const float*)d_in[4];
    float* out = (float*)d_out;

    unsigned short* xb  = (unsigned short*)d_ws;                 // 16 MB
    unsigned short* Wt  = xb + (size_t)N_TOK * D_IN;             // 16 MB
    float*          g_t = (float*)(Wt + (size_t)D_OUT * KTOT);   // 256 KB

    prep_kernel<<<4096, 256, 0, stream>>>(x, gW, gb, W, xb, Wt, g_t);
    moe_gemm13_kernel<<<dim3(D_OUT / BN, N_TOK / BM), 512, 0, stream>>>(
        xb, Wt, b, g_t, out);
}